// Round 1
// baseline (399.129 us; speedup 1.0000x reference)
//
#include <hip/hip_runtime.h>
#include <hip/hip_bf16.h>

#define B_ROWS 65536
#define D_DIM  1024
#define NC     120   // real output cols: 100 expert units + 2*10 gate logits
#define NCP    128   // padded
#define MBLK   64    // rows per workgroup
#define BK     64    // K chunk
#define ASTR   72    // LDS stride in shorts (16B-aligned rows, ~2-way banks)
#define CSTR   121   // LDS C stride in floats (odd -> conflict-free epilogue)

typedef __attribute__((ext_vector_type(4))) float f32x4;
typedef __attribute__((ext_vector_type(8))) short bf16x8;

__device__ __forceinline__ unsigned short f2bf(float f) {
  union { float f; unsigned u; } v; v.f = f;
  unsigned r = v.u + 0x7FFFu + ((v.u >> 16) & 1u);  // RNE
  return (unsigned short)(r >> 16);
}

// Pack expert_w [E=10][D=1024][U=10] and gate_w [T=2][D=1024][E=10]
// into Wt[c][d] bf16, c in 0..127 (B^T layout), cols 120..127 = 0.
__global__ __launch_bounds__(256) void pack_w(const float* __restrict__ ew,
                                              const float* __restrict__ gw,
                                              short* __restrict__ wt) {
  int idx = blockIdx.x * 256 + threadIdx.x;   // 128*1024 = 131072 total
  int c = idx >> 10, d = idx & 1023;
  float v = 0.f;
  if (c < 100) {
    int e = c / 10, u = c % 10;
    v = ew[(e * D_DIM + d) * 10 + u];
  } else if (c < NC) {
    int q = c - 100; int t = q / 10, e = q % 10;
    v = gw[(t * D_DIM + d) * 10 + e];
  }
  wt[c * D_DIM + d] = (short)f2bf(v);
}

union Smem {
  struct { short A[MBLK * ASTR]; short Bm[NCP * ASTR]; } s;  // 9216+18432 shorts -> 27648 B
  float C[MBLK * CSTR];                                      // 30976 B
};

__global__ __launch_bounds__(256) void mmoe_main(
    const float* __restrict__ x, const short* __restrict__ wt,
    const float* __restrict__ eb, const float* __restrict__ gb,
    const float* __restrict__ ctr_w, const float* __restrict__ ctr_b,
    const float* __restrict__ cvr_w, const float* __restrict__ cvr_b,
    float* __restrict__ out) {
  __shared__ Smem sm;
  const int tid  = threadIdx.x;
  const int wave = tid >> 6, lane = tid & 63;
  const int m0   = blockIdx.x * MBLK;

  // A staging: thread covers 4 float4 units; 16 threads per 64-float row
  const int arow = tid >> 4;          // + j*16
  const int akp  = (tid & 15) * 4;
  // B staging: 8 threads per 64-short col row of Wt
  const int bc   = tid >> 3;          // + j*32
  const int bks  = (tid & 7) * 8;

  const int lhi = lane >> 4;          // 0..3 (quad)
  const int llo = lane & 15;

  f32x4 acc[8];
  const f32x4 vzero = {0.f, 0.f, 0.f, 0.f};
  #pragma unroll
  for (int i = 0; i < 8; ++i) acc[i] = vzero;

  for (int k0 = 0; k0 < D_DIM; k0 += BK) {
    __syncthreads();
    // ---- stage A: 64 rows x 64 cols fp32 -> bf16 LDS
    #pragma unroll
    for (int j = 0; j < 4; ++j) {
      const int row = j * 16 + arow;
      const float4 v = *reinterpret_cast<const float4*>(
          x + (size_t)(m0 + row) * D_DIM + k0 + akp);
      ushort4 h;
      h.x = f2bf(v.x); h.y = f2bf(v.y); h.z = f2bf(v.z); h.w = f2bf(v.w);
      *reinterpret_cast<ushort4*>(&sm.s.A[row * ASTR + akp]) = h;
    }
    // ---- stage B: 128 cols x 64 k bf16 (already bf16 in Wt)
    #pragma unroll
    for (int j = 0; j < 4; ++j) {
      const int c = j * 32 + bc;
      const uint4 v = *reinterpret_cast<const uint4*>(wt + c * D_DIM + k0 + bks);
      *reinterpret_cast<uint4*>(&sm.s.Bm[c * ASTR + bks]) = v;
    }
    __syncthreads();
    // ---- MFMA: wave handles rows wave*16..+15, all 128 cols
    #pragma unroll
    for (int ks = 0; ks < BK; ks += 32) {
      const bf16x8 af = *reinterpret_cast<const bf16x8*>(
          &sm.s.A[(wave * 16 + llo) * ASTR + ks + lhi * 8]);
      #pragma unroll
      for (int ct = 0; ct < 8; ++ct) {
        const bf16x8 bf = *reinterpret_cast<const bf16x8*>(
            &sm.s.Bm[(ct * 16 + llo) * ASTR + ks + lhi * 8]);
        acc[ct] = __builtin_amdgcn_mfma_f32_16x16x32_bf16(af, bf, acc[ct], 0, 0, 0);
      }
    }
  }

  __syncthreads();
  // scatter C frags -> LDS rows (C/D: col=lane&15, row=quad*4+reg)
  #pragma unroll
  for (int ct = 0; ct < 8; ++ct) {
    const int col = ct * 16 + llo;
    if (col < NC) {
      #pragma unroll
      for (int r = 0; r < 4; ++r) {
        const int row = wave * 16 + lhi * 4 + r;
        sm.C[row * CSTR + col] = acc[ct][r];
      }
    }
  }
  __syncthreads();

  // epilogue: one thread per row
  if (tid < MBLK) {
    const float* crow = &sm.C[tid * CSTR];
    float w0[10], w1[10];
    #pragma unroll
    for (int u = 0; u < 10; ++u) { w0[u] = ctr_w[u]; w1[u] = cvr_w[u]; }
    // s{0,1}[e] = sum_u relu(expert[e,u]) * w[u]
    float s0[10], s1[10];
    #pragma unroll
    for (int e = 0; e < 10; ++e) {
      float a0 = 0.f, a1 = 0.f;
      #pragma unroll
      for (int u = 0; u < 10; ++u) {
        float v = crow[e * 10 + u] + eb[e * 10 + u];
        v = fmaxf(v, 0.f);
        a0 = fmaf(v, w0[u], a0);
        a1 = fmaf(v, w1[u], a1);
      }
      s0[e] = a0; s1[e] = a1;
    }
    // task 0: softmax over gate logits, combine, sigmoid
    {
      float gl[10], mx = -1e30f;
      #pragma unroll
      for (int e = 0; e < 10; ++e) { gl[e] = crow[100 + e] + gb[e]; mx = fmaxf(mx, gl[e]); }
      float den = 0.f, num = 0.f;
      #pragma unroll
      for (int e = 0; e < 10; ++e) {
        float p = __expf(gl[e] - mx); den += p; num = fmaf(p, s0[e], num);
      }
      float z = num / den + ctr_b[0];
      out[m0 + tid] = 1.f / (1.f + __expf(-z));
    }
    // task 1
    {
      float gl[10], mx = -1e30f;
      #pragma unroll
      for (int e = 0; e < 10; ++e) { gl[e] = crow[110 + e] + gb[10 + e]; mx = fmaxf(mx, gl[e]); }
      float den = 0.f, num = 0.f;
      #pragma unroll
      for (int e = 0; e < 10; ++e) {
        float p = __expf(gl[e] - mx); den += p; num = fmaf(p, s1[e], num);
      }
      float z = num / den + cvr_b[0];
      out[B_ROWS + m0 + tid] = 1.f / (1.f + __expf(-z));
    }
  }
}

extern "C" void kernel_launch(void* const* d_in, const int* in_sizes, int n_in,
                              void* d_out, int out_size, void* d_ws, size_t ws_size,
                              hipStream_t stream) {
  const float* x     = (const float*)d_in[0];
  // d_in[1] show_index, d_in[2] st: unused by the reference math
  const float* ew    = (const float*)d_in[3];
  const float* eb    = (const float*)d_in[4];
  const float* gw    = (const float*)d_in[5];
  const float* gb    = (const float*)d_in[6];
  const float* ctr_w = (const float*)d_in[7];
  const float* ctr_b = (const float*)d_in[8];
  const float* cvr_w = (const float*)d_in[9];
  const float* cvr_b = (const float*)d_in[10];
  float* out = (float*)d_out;
  short* wt  = (short*)d_ws;  // 128*1024 bf16 = 256 KB

  pack_w<<<512, 256, 0, stream>>>(ew, gw, wt);
  mmoe_main<<<B_ROWS / MBLK, 256, 0, stream>>>(x, wt, eb, gb, ctr_w, ctr_b,
                                               cvr_w, cvr_b, out);
}